// Round 2
// baseline (664.587 us; speedup 1.0000x reference)
//
#include <hip/hip_runtime.h>

// QECC statevector: 23 qubits, DIM = 2^23 amplitudes, N0 = 2 vectors per code.
// Gate ind0 acts on statevector bit p = 22 - ind0:  new_d = sum_b old_b * U[b,d].
// Split: k_low does statevector bits 0..12 (gates q=22..10), k_high bits 13..22
// (gates q=9..0) + fused overlap dot. Intermediate ws is TRANSPOSED:
//   W(i,h,l) = i*DIM + (l>>3)*8192 + h*8 + (l&7)     (h = idx>>13, l = idx&8191)
// so k_high reads one contiguous 64 KB chunk per (block,i).
#define DIM_ (1 << 23)
#define N0_ 2

// overlap accumulators {R00,I00,R01,I01,R10,I10,R11,I11}; zeroed each launch
__device__ float g_acc[8];

// LDS bank swizzle (bits 0,1 ^= bits 5,6 ; bits 2..4 ^= bits 7..9), bijective.
// Verified round 1: SQ_LDS_BANK_CONFLICT == 0.
__device__ __forceinline__ int swz(int x) {
    return x ^ ((x >> 5) & 3) ^ (((x >> 7) & 7) << 2);
}

__device__ __forceinline__ void gload(const float* __restrict__ ur,
                                      const float* __restrict__ ui, int q,
                                      float2& u00, float2& u01, float2& u10, float2& u11) {
    u00 = make_float2(ur[q * 4 + 0], ui[q * 4 + 0]);
    u01 = make_float2(ur[q * 4 + 1], ui[q * 4 + 1]);
    u10 = make_float2(ur[q * 4 + 2], ui[q * 4 + 2]);
    u11 = make_float2(ur[q * 4 + 3], ui[q * 4 + 3]);
}

// out0 = u00*a0 + u10*a1 ; out1 = u01*a0 + u11*a1   (complex, einsum convention)
__device__ __forceinline__ void bfly(float2& a0, float2& a1,
                                     float2 u00, float2 u01, float2 u10, float2 u11) {
    float2 n0, n1;
    n0.x = a0.x * u00.x - a0.y * u00.y + a1.x * u10.x - a1.y * u10.y;
    n0.y = a0.x * u00.y + a0.y * u00.x + a1.x * u10.y + a1.y * u10.x;
    n1.x = a0.x * u01.x - a0.y * u01.y + a1.x * u11.x - a1.y * u11.y;
    n1.y = a0.x * u01.y + a0.y * u01.x + a1.x * u11.y + a1.y * u11.x;
    a0 = n0; a1 = n1;
}

// Butterfly all pairs of the 16-register file v[] differing in bit log2(S), gate Q.
#define BFLY16(S, Q)                                                           \
    do {                                                                       \
        float2 u00, u01, u10, u11;                                             \
        gload(ur, ui, (Q), u00, u01, u10, u11);                                \
        _Pragma("unroll")                                                      \
        for (int m0 = 0; m0 < 16; ++m0)                                        \
            if (!(m0 & (S))) bfly(v[m0], v[m0 + (S)], u00, u01, u10, u11);     \
    } while (0)

// ---------------------------------------------------------------------------
// K1: low 13 bits. Block (H, i) owns the contiguous chunk idx = H*8192 + l.
// 512 thr x 16 complex regs. Phases (4 bits each in regs, LDS remaps between):
//   A: l bits {0,1,11,12} -> q22,q21,q11,q10      (from float4 load layout)
//   B: l bits {2..5}      -> q20..q17
//   C: l bits {6..9}      -> q16..q13
//   readout: pairs (x, x^1024) -> q12, then store transposed (or identity for
//   the in-place fallback).
// ---------------------------------------------------------------------------
template <bool INTER>
__global__ __launch_bounds__(512, 4) void k_low(
    const float* __restrict__ inr, const float* __restrict__ ini,
    const float* __restrict__ ur, const float* __restrict__ ui,
    float2* __restrict__ outI, float* __restrict__ outR, float* __restrict__ outJ) {
    __shared__ float2 buf[8192];  // 64 KB
    const int t = threadIdx.x;
    const int H = blockIdx.x;                 // high-10-bit value this block owns
    const int base = blockIdx.y * DIM_ + (H << 13);

    float2 v[16];
    // load: reg m = (k<<2)|j  <->  l = (k<<11)|(t<<2)|j
#pragma unroll
    for (int k = 0; k < 4; ++k) {
        const int y = (k << 11) | (t << 2);
        const float4 re = *(const float4*)(inr + base + y);
        const float4 im = *(const float4*)(ini + base + y);
        v[k * 4 + 0] = make_float2(re.x, im.x);
        v[k * 4 + 1] = make_float2(re.y, im.y);
        v[k * 4 + 2] = make_float2(re.z, im.z);
        v[k * 4 + 3] = make_float2(re.w, im.w);
    }
    // Phase A: m0=l0->q22, m1=l1->q21, m2=l11->q11, m3=l12->q10
    BFLY16(1, 22);
    BFLY16(2, 21);
    BFLY16(4, 11);
    BFLY16(8, 10);
#pragma unroll
    for (int m = 0; m < 16; ++m)
        buf[swz(((m >> 2) << 11) | (t << 2) | (m & 3))] = v[m];
    __syncthreads();
    // Phase B: m = l bits 2..5 ; x = (t&3) | (m<<2) | ((t>>2)<<6)
#pragma unroll
    for (int m = 0; m < 16; ++m)
        v[m] = buf[swz((t & 3) | (m << 2) | ((t >> 2) << 6))];
    BFLY16(1, 20);
    BFLY16(2, 19);
    BFLY16(4, 18);
    BFLY16(8, 17);
#pragma unroll
    for (int m = 0; m < 16; ++m)
        buf[swz((t & 3) | (m << 2) | ((t >> 2) << 6))] = v[m];  // same slots: no race
    __syncthreads();
    // Phase C: m = l bits 6..9 ; x = (t&63) | (m<<6) | ((t>>6)<<10)
#pragma unroll
    for (int m = 0; m < 16; ++m)
        v[m] = buf[swz((t & 63) | (m << 6) | ((t >> 6) << 10))];
    BFLY16(1, 16);
    BFLY16(2, 15);
    BFLY16(4, 14);
    BFLY16(8, 13);
#pragma unroll
    for (int m = 0; m < 16; ++m)
        buf[swz((t & 63) | (m << 6) | ((t >> 6) << 10))] = v[m];
    __syncthreads();
    // Readout + q12 (l bit 10 = pairs x, x^1024), stores 2 complex per float4.
    {
        float2 u00, u01, u10, u11;
        gload(ur, ui, 12, u00, u01, u10, u11);
#pragma unroll
        for (int rp = 0; rp < 4; ++rp) {
            const int x0 = (rp << 11) | (t << 1);  // even, bit10 = 0
            float2 a0 = buf[swz(x0)];
            float2 a1 = buf[swz(x0 | 1)];
            float2 b0 = buf[swz(x0 | 1024)];
            float2 b1 = buf[swz(x0 | 1025)];
            bfly(a0, b0, u00, u01, u10, u11);
            bfly(a1, b1, u00, u01, u10, u11);
            if (INTER) {
                // transposed: o = (l>>3)*8192 + H*8 + (l&7); l&7 even -> 16B aligned
                const int l0 = x0, l1 = x0 | 1024;
                const int o0 = ((l0 >> 3) << 13) | (H << 3) | (l0 & 7);
                const int o1 = ((l1 >> 3) << 13) | (H << 3) | (l1 & 7);
                float2* p = outI + blockIdx.y * DIM_;
                *(float4*)(p + o0) = make_float4(a0.x, a0.y, a1.x, a1.y);
                *(float4*)(p + o1) = make_float4(b0.x, b0.y, b1.x, b1.y);
            } else {
                // identity layout, in-place safe (block writes only its own chunk)
                *(float2*)(outR + base + x0) = make_float2(a0.x, a1.x);
                *(float2*)(outJ + base + x0) = make_float2(a0.y, a1.y);
                *(float2*)(outR + base + (x0 | 1024)) = make_float2(b0.x, b1.x);
                *(float2*)(outJ + base + (x0 | 1024)) = make_float2(b0.y, b1.y);
            }
        }
    }
}

// ---------------------------------------------------------------------------
// K2: high 10 bits (gates q=9..0) + fused overlap dot. Block g owns l-group
// l = g*8 + e. INTER path reads one contiguous 64 KB ws chunk per (g,i).
// local y = h*8 + e (13 bits). Phases:
//   A: y bits {11,12} = h bits {8,9} -> q1,q0    (from load layout)
//   B: h bits 0..3 -> q9..q6
//   C: h bits 4..7 -> q5..q2 ; then dot straight from registers.
// ---------------------------------------------------------------------------
template <bool INTER>
__global__ __launch_bounds__(512, 4) void k_high(
    const float2* __restrict__ wsI, const float* __restrict__ wsR, const float* __restrict__ wsJ,
    const float* __restrict__ c1r, const float* __restrict__ c1i,
    const float* __restrict__ ur, const float* __restrict__ ui) {
    __shared__ float2 buf[8192];  // 64 KB; reused as reduction scratch
    const int t = threadIdx.x;
    const int g = blockIdx.x;  // l-group, 1024 blocks
    float acc[8] = {0.f, 0.f, 0.f, 0.f, 0.f, 0.f, 0.f, 0.f};

    for (int i = 0; i < 2; ++i) {
        float2 v[16];  // reg m: m0=y0, m1=y1, m{2,3}=y{11,12}
        if (INTER) {
            const float4* wsv = (const float4*)(wsI + i * DIM_ + (g << 13));
#pragma unroll
            for (int k = 0; k < 4; ++k)
#pragma unroll
                for (int jh = 0; jh < 2; ++jh) {
                    const float4 f = wsv[(k << 10) | (t << 1) | jh];
                    v[k * 4 + jh * 2 + 0] = make_float2(f.x, f.y);
                    v[k * 4 + jh * 2 + 1] = make_float2(f.z, f.w);
                }
        } else {
            // identity-layout fallback: idx = h*8192 + g*8 + e
#pragma unroll
            for (int k = 0; k < 4; ++k) {
                const int y0 = (k << 11) | (t << 2);
                const int a = ((y0 >> 3) << 13) | (g << 3) | (y0 & 7);
                const float4 re = *(const float4*)(wsR + i * DIM_ + a);
                const float4 im = *(const float4*)(wsJ + i * DIM_ + a);
                v[k * 4 + 0] = make_float2(re.x, im.x);
                v[k * 4 + 1] = make_float2(re.y, im.y);
                v[k * 4 + 2] = make_float2(re.z, im.z);
                v[k * 4 + 3] = make_float2(re.w, im.w);
            }
        }
        // Phase A: h bits 8,9 -> gates q1,q0
        BFLY16(4, 1);
        BFLY16(8, 0);
#pragma unroll
        for (int m = 0; m < 16; ++m)
            buf[swz(((m >> 2) << 11) | (t << 2) | (m & 3))] = v[m];
        __syncthreads();
        // Phase B: m = h bits 0..3 = y bits 3..6 ; x = (t&7) | (m<<3) | ((t>>3)<<7)
#pragma unroll
        for (int m = 0; m < 16; ++m)
            v[m] = buf[swz((t & 7) | (m << 3) | ((t >> 3) << 7))];
        BFLY16(1, 9);
        BFLY16(2, 8);
        BFLY16(4, 7);
        BFLY16(8, 6);
#pragma unroll
        for (int m = 0; m < 16; ++m)
            buf[swz((t & 7) | (m << 3) | ((t >> 3) << 7))] = v[m];  // same slots
        __syncthreads();
        // Phase C: m = h bits 4..7 = y bits 7..10 ; x = (t&127) | (m<<7) | ((t>>7)<<11)
#pragma unroll
        for (int m = 0; m < 16; ++m)
            v[m] = buf[swz((t & 127) | (m << 7) | ((t >> 7) << 11))];
        BFLY16(1, 5);
        BFLY16(2, 4);
        BFLY16(4, 3);
        BFLY16(8, 2);
        // Fused dot: overlap_ij += conj(c0'_i) * c1_j, straight from registers.
#pragma unroll
        for (int m = 0; m < 16; ++m) {
            const int y = (t & 127) | (m << 7) | ((t >> 7) << 11);
            const int idx = ((y >> 3) << 13) | (g << 3) | (y & 7);
            const float ar = c1r[idx], ai = c1i[idx];
            const float br = c1r[DIM_ + idx], bi = c1i[DIM_ + idx];
            acc[i * 4 + 0] += v[m].x * ar + v[m].y * ai;
            acc[i * 4 + 1] += v[m].x * ai - v[m].y * ar;
            acc[i * 4 + 2] += v[m].x * br + v[m].y * bi;
            acc[i * 4 + 3] += v[m].x * bi - v[m].y * br;
        }
        __syncthreads();  // buf reused by next i / reduction
    }
    // wave (64) shuffle reduce -> cross-wave LDS -> one atomic per block
#pragma unroll
    for (int k = 0; k < 8; ++k)
#pragma unroll
        for (int off = 32; off > 0; off >>= 1)
            acc[k] += __shfl_down(acc[k], off, 64);
    float* red = (float*)buf;
    const int wave = t >> 6, lane = t & 63;
    if (lane == 0) {
#pragma unroll
        for (int k = 0; k < 8; ++k) red[wave * 8 + k] = acc[k];
    }
    __syncthreads();
    if (t < 8) {
        float s = 0.f;
#pragma unroll
        for (int w = 0; w < 8; ++w) s += red[w * 8 + t];
        atomicAdd(&g_acc[t], s);
    }
}

__global__ void k_zero() {
    if (threadIdx.x < 8) g_acc[threadIdx.x] = 0.f;
}

__global__ void k_fin(float* __restrict__ out) {
    if (threadIdx.x == 0) {
        float s = 0.f;
#pragma unroll
        for (int k = 0; k < 4; ++k)
            s += g_acc[2 * k] * g_acc[2 * k] + g_acc[2 * k + 1] * g_acc[2 * k + 1];
        out[0] = (float)N0_ - s;
    }
}

extern "C" void kernel_launch(void* const* d_in, const int* in_sizes, int n_in,
                              void* d_out, int out_size, void* d_ws, size_t ws_size,
                              hipStream_t stream) {
    const float* c0r = (const float*)d_in[0];
    const float* c0i = (const float*)d_in[1];
    const float* c1r = (const float*)d_in[2];
    const float* c1i = (const float*)d_in[3];
    const float* ur  = (const float*)d_in[4];
    const float* ui  = (const float*)d_in[5];
    float* out = (float*)d_out;

    const size_t need = (size_t)N0_ * DIM_ * sizeof(float2);  // 128 MB intermediate
    k_zero<<<1, 64, 0, stream>>>();
    dim3 g1(1024, N0_);
    if (d_ws != nullptr && ws_size >= need) {
        float2* wsI = (float2*)d_ws;
        k_low<true><<<g1, 512, 0, stream>>>(c0r, c0i, ur, ui, wsI, nullptr, nullptr);
        k_high<true><<<1024, 512, 0, stream>>>(wsI, nullptr, nullptr, c1r, c1i, ur, ui);
    } else {
        // fallback: identity layout, in place into code0 planes (harness restores
        // d_in from pristine copies before every timed launch)
        float* oR = (float*)c0r;
        float* oJ = (float*)c0i;
        k_low<false><<<g1, 512, 0, stream>>>(c0r, c0i, ur, ui, nullptr, oR, oJ);
        k_high<false><<<1024, 512, 0, stream>>>(nullptr, oR, oJ, c1r, c1i, ur, ui);
    }
    k_fin<<<1, 64, 0, stream>>>(out);
}

// Round 3
// 419.374 us; speedup vs baseline: 1.5847x; 1.5847x over previous
//
#include <hip/hip_runtime.h>

// QECC statevector: 23 qubits, DIM = 2^23 amplitudes, N0 = 2 vectors per code.
// Gate ind0 acts on statevector bit p = 22 - ind0:  new_d = sum_b old_b * U[b,d].
// Split: k_low does statevector bits 0..12 (gates q=22..10), k_high bits 13..22
// (gates q=9..0) + fused overlap dot. Intermediate ws is TRANSPOSED:
//   W(i,h,l) = i*DIM + (l>>3)*8192 + h*8 + (l&7)     (h = idx>>13, l = idx&8191)
// so k_high reads one contiguous 64 KB chunk per (block,i).
//
// NOTE on __launch_bounds__: measured R2 showed hipcc treats the 2nd arg as
// CUDA-style min BLOCKS per CU: (512,4) -> 32 waves/CU -> 64-VGPR cap -> 401 MB
// of spill traffic. (512,2) -> cap >=128 under either interpretation; LDS
// (64 KB/block) limits us to 2 blocks/CU anyway.
#define DIM_ (1 << 23)
#define N0_ 2

// overlap accumulators {R00,I00,R01,I01,R10,I10,R11,I11}; zeroed each launch
__device__ float g_acc[8];

// LDS bank swizzle (bits 0,1 ^= bits 5,6 ; bits 2..4 ^= bits 7..9), bijective.
__device__ __forceinline__ int swz(int x) {
    return x ^ ((x >> 5) & 3) ^ (((x >> 7) & 7) << 2);
}

__device__ __forceinline__ void gload(const float* __restrict__ ur,
                                      const float* __restrict__ ui, int q,
                                      float2& u00, float2& u01, float2& u10, float2& u11) {
    u00 = make_float2(ur[q * 4 + 0], ui[q * 4 + 0]);
    u01 = make_float2(ur[q * 4 + 1], ui[q * 4 + 1]);
    u10 = make_float2(ur[q * 4 + 2], ui[q * 4 + 2]);
    u11 = make_float2(ur[q * 4 + 3], ui[q * 4 + 3]);
}

// out0 = u00*a0 + u10*a1 ; out1 = u01*a0 + u11*a1   (complex, einsum convention)
__device__ __forceinline__ void bfly(float2& a0, float2& a1,
                                     float2 u00, float2 u01, float2 u10, float2 u11) {
    float2 n0, n1;
    n0.x = a0.x * u00.x - a0.y * u00.y + a1.x * u10.x - a1.y * u10.y;
    n0.y = a0.x * u00.y + a0.y * u00.x + a1.x * u10.y + a1.y * u10.x;
    n1.x = a0.x * u01.x - a0.y * u01.y + a1.x * u11.x - a1.y * u11.y;
    n1.y = a0.x * u01.y + a0.y * u01.x + a1.x * u11.y + a1.y * u11.x;
    a0 = n0; a1 = n1;
}

// Butterfly all pairs of the 16-register file v[] differing in bit log2(S), gate Q.
#define BFLY16(S, Q)                                                           \
    do {                                                                       \
        float2 u00, u01, u10, u11;                                             \
        gload(ur, ui, (Q), u00, u01, u10, u11);                                \
        _Pragma("unroll")                                                      \
        for (int m0 = 0; m0 < 16; ++m0)                                        \
            if (!(m0 & (S))) bfly(v[m0], v[m0 + (S)], u00, u01, u10, u11);     \
    } while (0)

// ---------------------------------------------------------------------------
// K1: low 13 bits. Block (H, i) owns the contiguous chunk idx = H*8192 + l.
// 512 thr x 16 complex regs. Phases (4 bits each in regs, LDS remaps between):
//   A: l bits {0,1,11,12} -> q22,q21,q11,q10      (from float4 load layout)
//   B: l bits {2..5}      -> q20..q17
//   C: l bits {6..9}      -> q16..q13
//   readout: pairs (x, x^1024) -> q12, then store transposed (or identity for
//   the in-place fallback).
// ---------------------------------------------------------------------------
template <bool INTER>
__global__ __launch_bounds__(512, 2) void k_low(
    const float* __restrict__ inr, const float* __restrict__ ini,
    const float* __restrict__ ur, const float* __restrict__ ui,
    float2* __restrict__ outI, float* __restrict__ outR, float* __restrict__ outJ) {
    __shared__ float2 buf[8192];  // 64 KB
    const int t = threadIdx.x;
    const int H = blockIdx.x;                 // high-10-bit value this block owns
    const int base = blockIdx.y * DIM_ + (H << 13);

    float2 v[16];
    // load: reg m = (k<<2)|j  <->  l = (k<<11)|(t<<2)|j
#pragma unroll
    for (int k = 0; k < 4; ++k) {
        const int y = (k << 11) | (t << 2);
        const float4 re = *(const float4*)(inr + base + y);
        const float4 im = *(const float4*)(ini + base + y);
        v[k * 4 + 0] = make_float2(re.x, im.x);
        v[k * 4 + 1] = make_float2(re.y, im.y);
        v[k * 4 + 2] = make_float2(re.z, im.z);
        v[k * 4 + 3] = make_float2(re.w, im.w);
    }
    // Phase A: m0=l0->q22, m1=l1->q21, m2=l11->q11, m3=l12->q10
    BFLY16(1, 22);
    BFLY16(2, 21);
    BFLY16(4, 11);
    BFLY16(8, 10);
#pragma unroll
    for (int m = 0; m < 16; ++m)
        buf[swz(((m >> 2) << 11) | (t << 2) | (m & 3))] = v[m];
    __syncthreads();
    // Phase B: m = l bits 2..5 ; x = (t&3) | (m<<2) | ((t>>2)<<6)
#pragma unroll
    for (int m = 0; m < 16; ++m)
        v[m] = buf[swz((t & 3) | (m << 2) | ((t >> 2) << 6))];
    BFLY16(1, 20);
    BFLY16(2, 19);
    BFLY16(4, 18);
    BFLY16(8, 17);
#pragma unroll
    for (int m = 0; m < 16; ++m)
        buf[swz((t & 3) | (m << 2) | ((t >> 2) << 6))] = v[m];  // same slots: no race
    __syncthreads();
    // Phase C: m = l bits 6..9 ; x = (t&63) | (m<<6) | ((t>>6)<<10)
#pragma unroll
    for (int m = 0; m < 16; ++m)
        v[m] = buf[swz((t & 63) | (m << 6) | ((t >> 6) << 10))];
    BFLY16(1, 16);
    BFLY16(2, 15);
    BFLY16(4, 14);
    BFLY16(8, 13);
#pragma unroll
    for (int m = 0; m < 16; ++m)
        buf[swz((t & 63) | (m << 6) | ((t >> 6) << 10))] = v[m];
    __syncthreads();
    // Readout + q12 (l bit 10 = pairs x, x^1024), stores 2 complex per float4.
    {
        float2 u00, u01, u10, u11;
        gload(ur, ui, 12, u00, u01, u10, u11);
#pragma unroll
        for (int rp = 0; rp < 4; ++rp) {
            const int x0 = (rp << 11) | (t << 1);  // even, bit10 = 0
            float2 a0 = buf[swz(x0)];
            float2 a1 = buf[swz(x0 | 1)];
            float2 b0 = buf[swz(x0 | 1024)];
            float2 b1 = buf[swz(x0 | 1025)];
            bfly(a0, b0, u00, u01, u10, u11);
            bfly(a1, b1, u00, u01, u10, u11);
            if (INTER) {
                // transposed: o = (l>>3)*8192 + H*8 + (l&7); l&7 even -> 16B aligned
                const int l0 = x0, l1 = x0 | 1024;
                const int o0 = ((l0 >> 3) << 13) | (H << 3) | (l0 & 7);
                const int o1 = ((l1 >> 3) << 13) | (H << 3) | (l1 & 7);
                float2* p = outI + blockIdx.y * DIM_;
                *(float4*)(p + o0) = make_float4(a0.x, a0.y, a1.x, a1.y);
                *(float4*)(p + o1) = make_float4(b0.x, b0.y, b1.x, b1.y);
            } else {
                // identity layout, in-place safe (block writes only its own chunk)
                *(float2*)(outR + base + x0) = make_float2(a0.x, a1.x);
                *(float2*)(outJ + base + x0) = make_float2(a0.y, a1.y);
                *(float2*)(outR + base + (x0 | 1024)) = make_float2(b0.x, b1.x);
                *(float2*)(outJ + base + (x0 | 1024)) = make_float2(b0.y, b1.y);
            }
        }
    }
}

// ---------------------------------------------------------------------------
// One 10-bit high-pass for vector i: loads 8192 complex, butterflies gates
// q=9..0, leaves the final values in v[] (phase-C register layout:
// y = (t&127) | (m<<7) | ((t>>7)<<11)). No trailing __syncthreads.
// ---------------------------------------------------------------------------
template <bool INTER>
__device__ __forceinline__ void high_pass(
    float2 (&v)[16], float2* buf, const int t, const int g, const int i,
    const float2* __restrict__ wsI, const float* __restrict__ wsR,
    const float* __restrict__ wsJ,
    const float* __restrict__ ur, const float* __restrict__ ui) {
    if constexpr (INTER) {
        const float4* wsv = (const float4*)(wsI + i * DIM_ + (g << 13));
#pragma unroll
        for (int k = 0; k < 4; ++k)
#pragma unroll
            for (int jh = 0; jh < 2; ++jh) {
                const float4 f = wsv[(k << 10) | (t << 1) | jh];
                v[k * 4 + jh * 2 + 0] = make_float2(f.x, f.y);
                v[k * 4 + jh * 2 + 1] = make_float2(f.z, f.w);
            }
    } else {
        // identity-layout fallback: idx = h*8192 + g*8 + e
#pragma unroll
        for (int k = 0; k < 4; ++k) {
            const int y0 = (k << 11) | (t << 2);
            const int a = ((y0 >> 3) << 13) | (g << 3) | (y0 & 7);
            const float4 re = *(const float4*)(wsR + i * DIM_ + a);
            const float4 im = *(const float4*)(wsJ + i * DIM_ + a);
            v[k * 4 + 0] = make_float2(re.x, im.x);
            v[k * 4 + 1] = make_float2(re.y, im.y);
            v[k * 4 + 2] = make_float2(re.z, im.z);
            v[k * 4 + 3] = make_float2(re.w, im.w);
        }
    }
    // Phase A: reg m2,m3 = y bits 11,12 = h bits 8,9 -> gates q1,q0
    BFLY16(4, 1);
    BFLY16(8, 0);
#pragma unroll
    for (int m = 0; m < 16; ++m)
        buf[swz(((m >> 2) << 11) | (t << 2) | (m & 3))] = v[m];
    __syncthreads();
    // Phase B: m = h bits 0..3 = y bits 3..6 ; x = (t&7) | (m<<3) | ((t>>3)<<7)
#pragma unroll
    for (int m = 0; m < 16; ++m)
        v[m] = buf[swz((t & 7) | (m << 3) | ((t >> 3) << 7))];
    BFLY16(1, 9);
    BFLY16(2, 8);
    BFLY16(4, 7);
    BFLY16(8, 6);
#pragma unroll
    for (int m = 0; m < 16; ++m)
        buf[swz((t & 7) | (m << 3) | ((t >> 3) << 7))] = v[m];  // same slots
    __syncthreads();
    // Phase C: m = h bits 4..7 = y bits 7..10 ; x = (t&127) | (m<<7) | ((t>>7)<<11)
#pragma unroll
    for (int m = 0; m < 16; ++m)
        v[m] = buf[swz((t & 127) | (m << 7) | ((t >> 7) << 11))];
    BFLY16(1, 5);
    BFLY16(2, 4);
    BFLY16(4, 3);
    BFLY16(8, 2);
}

// ---------------------------------------------------------------------------
// K2: high 10 bits (gates q=9..0) + fused overlap dot. Block g owns l-group
// l = g*8 + e. Transforms i=0 into v0, i=1 into v1 (both held in registers),
// then a SINGLE dot loop reading c1 once.
// ---------------------------------------------------------------------------
template <bool INTER>
__global__ __launch_bounds__(512, 2) void k_high(
    const float2* __restrict__ wsI, const float* __restrict__ wsR, const float* __restrict__ wsJ,
    const float* __restrict__ c1r, const float* __restrict__ c1i,
    const float* __restrict__ ur, const float* __restrict__ ui) {
    __shared__ float2 buf[8192];  // 64 KB; reused as reduction scratch
    const int t = threadIdx.x;
    const int g = blockIdx.x;  // l-group, 1024 blocks
    float acc[8];
#pragma unroll
    for (int k = 0; k < 8; ++k) acc[k] = 0.f;

    float2 v0[16], v1[16];
    high_pass<INTER>(v0, buf, t, g, 0, wsI, wsR, wsJ, ur, ui);
    __syncthreads();  // buf handoff between passes
    high_pass<INTER>(v1, buf, t, g, 1, wsI, wsR, wsJ, ur, ui);

    // Fused dot: overlap_ij += conj(c0'_i) * c1_j ; c1 read ONCE.
#pragma unroll
    for (int m = 0; m < 16; ++m) {
        const int y = (t & 127) | (m << 7) | ((t >> 7) << 11);
        const int idx = ((y >> 3) << 13) | (g << 3) | (y & 7);
        const float ar = c1r[idx], ai = c1i[idx];
        const float br = c1r[DIM_ + idx], bi = c1i[DIM_ + idx];
        acc[0] += v0[m].x * ar + v0[m].y * ai;
        acc[1] += v0[m].x * ai - v0[m].y * ar;
        acc[2] += v0[m].x * br + v0[m].y * bi;
        acc[3] += v0[m].x * bi - v0[m].y * br;
        acc[4] += v1[m].x * ar + v1[m].y * ai;
        acc[5] += v1[m].x * ai - v1[m].y * ar;
        acc[6] += v1[m].x * br + v1[m].y * bi;
        acc[7] += v1[m].x * bi - v1[m].y * br;
    }

    // wave (64) shuffle reduce -> cross-wave LDS -> one atomic per block
#pragma unroll
    for (int k = 0; k < 8; ++k)
#pragma unroll
        for (int off = 32; off > 0; off >>= 1)
            acc[k] += __shfl_down(acc[k], off, 64);
    __syncthreads();  // all waves past their buf reads before reuse as scratch
    float* red = (float*)buf;
    const int wave = t >> 6, lane = t & 63;
    if (lane == 0) {
#pragma unroll
        for (int k = 0; k < 8; ++k) red[wave * 8 + k] = acc[k];
    }
    __syncthreads();
    if (t < 8) {
        float s = 0.f;
#pragma unroll
        for (int w = 0; w < 8; ++w) s += red[w * 8 + t];
        atomicAdd(&g_acc[t], s);
    }
}

__global__ void k_zero() {
    if (threadIdx.x < 8) g_acc[threadIdx.x] = 0.f;
}

__global__ void k_fin(float* __restrict__ out) {
    if (threadIdx.x == 0) {
        float s = 0.f;
#pragma unroll
        for (int k = 0; k < 4; ++k)
            s += g_acc[2 * k] * g_acc[2 * k] + g_acc[2 * k + 1] * g_acc[2 * k + 1];
        out[0] = (float)N0_ - s;
    }
}

extern "C" void kernel_launch(void* const* d_in, const int* in_sizes, int n_in,
                              void* d_out, int out_size, void* d_ws, size_t ws_size,
                              hipStream_t stream) {
    const float* c0r = (const float*)d_in[0];
    const float* c0i = (const float*)d_in[1];
    const float* c1r = (const float*)d_in[2];
    const float* c1i = (const float*)d_in[3];
    const float* ur  = (const float*)d_in[4];
    const float* ui  = (const float*)d_in[5];
    float* out = (float*)d_out;

    const size_t need = (size_t)N0_ * DIM_ * sizeof(float2);  // 128 MB intermediate
    k_zero<<<1, 64, 0, stream>>>();
    dim3 g1(1024, N0_);
    if (d_ws != nullptr && ws_size >= need) {
        float2* wsI = (float2*)d_ws;
        k_low<true><<<g1, 512, 0, stream>>>(c0r, c0i, ur, ui, wsI, nullptr, nullptr);
        k_high<true><<<1024, 512, 0, stream>>>(wsI, nullptr, nullptr, c1r, c1i, ur, ui);
    } else {
        // fallback: identity layout, in place into code0 planes (harness restores
        // d_in from pristine copies before every timed launch)
        float* oR = (float*)c0r;
        float* oJ = (float*)c0i;
        k_low<false><<<g1, 512, 0, stream>>>(c0r, c0i, ur, ui, nullptr, oR, oJ);
        k_high<false><<<1024, 512, 0, stream>>>(nullptr, oR, oJ, c1r, c1i, ur, ui);
    }
    k_fin<<<1, 64, 0, stream>>>(out);
}